// Round 1
// baseline (120.624 us; speedup 1.0000x reference)
//
#include <hip/hip_runtime.h>
#include <hip/hip_bf16.h>
#include <stdint.h>

#define GAMMA 1e-4f

typedef __bf16 bf16x8 __attribute__((ext_vector_type(8)));
typedef float f32x4 __attribute__((ext_vector_type(4)));

__device__ __forceinline__ unsigned short f2bf(float f) {
  __hip_bfloat16 h = __float2bfloat16(f);
  unsigned short u;
  __builtin_memcpy(&u, &h, 2);
  return u;
}

// ---------------- Kernel 1: 2x2 stride-2 conv -> bf16 feats + ||f||^2 ----------------
__global__ __launch_bounds__(256) void conv_feats_k(
    const float* __restrict__ x, const float* __restrict__ cw,
    const float* __restrict__ cb, __hip_bfloat16* __restrict__ feats,
    float* __restrict__ f2) {
  const int b = blockIdx.x, tid = threadIdx.x;
  __shared__ float swb[20];
  if (tid < 16) swb[tid] = cw[tid];
  else if (tid < 20) swb[tid] = cb[tid - 16];
  __syncthreads();
  float w[16], bias[4];
#pragma unroll
  for (int i = 0; i < 16; i++) w[i] = swb[i];
#pragma unroll
  for (int c = 0; c < 4; c++) bias[c] = swb[16 + c];
  const float* xb = x + (size_t)b * 4096;
  __hip_bfloat16* fb = feats + (size_t)b * 4096;
  float ssq = 0.f;
#pragma unroll
  for (int k = 0; k < 4; k++) {
    int p = tid + k * 256;         // output position 0..1023
    int h = p >> 5, wcol = p & 31;
    float2 t0 = *(const float2*)(xb + (2 * h) * 64 + 2 * wcol);
    float2 t1 = *(const float2*)(xb + (2 * h + 1) * 64 + 2 * wcol);
#pragma unroll
    for (int c = 0; c < 4; c++) {
      float v = bias[c] + t0.x * w[c * 4 + 0] + t0.y * w[c * 4 + 1]
                        + t1.x * w[c * 4 + 2] + t1.y * w[c * 4 + 3];
      fb[c * 1024 + p] = __float2bfloat16(v);
      ssq += v * v;
    }
  }
  for (int off = 32; off > 0; off >>= 1) ssq += __shfl_down(ssq, off);
  __shared__ float red[4];
  if ((tid & 63) == 0) red[tid >> 6] = ssq;
  __syncthreads();
  if (tid == 0) f2[b] = red[0] + red[1] + red[2] + red[3];
}

// ---------------- Kernel 2: prototypes -> bf16 + ||p||^2 ----------------
__global__ __launch_bounds__(256) void proto_prep_k(
    const float* __restrict__ pr, __hip_bfloat16* __restrict__ pb,
    float* __restrict__ p2) {
  const int j = blockIdx.x, tid = threadIdx.x;
  const float4* src = (const float4*)(pr + (size_t)j * 4096);
  ushort4* dst = (ushort4*)(pb + (size_t)j * 4096);
  float ssq = 0.f;
#pragma unroll
  for (int k = 0; k < 4; k++) {
    float4 v = src[tid + k * 256];
    ssq += v.x * v.x + v.y * v.y + v.z * v.z + v.w * v.w;
    ushort4 u;
    u.x = f2bf(v.x); u.y = f2bf(v.y); u.z = f2bf(v.z); u.w = f2bf(v.w);
    dst[tid + k * 256] = u;
  }
  for (int off = 32; off > 0; off >>= 1) ssq += __shfl_down(ssq, off);
  __shared__ float red[4];
  if ((tid & 63) == 0) red[tid >> 6] = ssq;
  __syncthreads();
  if (tid == 0) p2[j] = red[0] + red[1] + red[2] + red[3];
}

// ---------------- Kernel 3: bf16 GEMM (feats x protos^T) + RBF epilogue ----------------
// 128x128 tile, BK=64, 4 waves (2x2), 16x16x32 MFMA, global_load_lds staging,
// XOR swizzle: phys = logical ^ ((row&7)<<4)  (rows are 128B) -> conflict-free frag reads.
#define SWZ(o) ((o) ^ ((((o) >> 7) & 7) << 4))

__global__ __launch_bounds__(256) void gemm_kv_k(
    const __hip_bfloat16* __restrict__ A, const __hip_bfloat16* __restrict__ B,
    const float* __restrict__ f2, const float* __restrict__ p2,
    float* __restrict__ kv) {
  __shared__ __align__(16) char lds[32768];  // A tile [0,16K), B tile [16K,32K)
  const int tid = threadIdx.x;
  const int wave = tid >> 6, lane = tid & 63;
  const int q = lane >> 4, l16 = lane & 15;
  const int bn = blockIdx.x, bm = blockIdx.y;
  const int wr = wave >> 1, wcid = wave & 1;

  // staging: chunk = i*256+tid -> linear LDS dest; global src pre-swizzled (rule #21)
  const __hip_bfloat16* agp[4];
  const __hip_bfloat16* bgp[4];
#pragma unroll
  for (int i = 0; i < 4; i++) {
    int loff = (i * 256 + tid) * 16;
    int logical = SWZ(loff);            // involution
    int row = logical >> 7;             // 0..127 (row bits untouched by SWZ)
    int kel = (logical & 127) >> 1;     // bf16 element within row
    agp[i] = A + (size_t)(bm * 128 + row) * 4096 + kel;
    bgp[i] = B + (size_t)(bn * 128 + row) * 4096 + kel;
  }

  f32x4 acc[4][4] = {};

  for (int kt = 0; kt < 64; ++kt) {
#pragma unroll
    for (int i = 0; i < 4; i++) {
      __builtin_amdgcn_global_load_lds(
          (__attribute__((address_space(1))) void*)(void*)(agp[i] + kt * 64),
          (__attribute__((address_space(3))) void*)(lds + i * 4096 + wave * 1024),
          16, 0, 0);
      __builtin_amdgcn_global_load_lds(
          (__attribute__((address_space(1))) void*)(void*)(bgp[i] + kt * 64),
          (__attribute__((address_space(3))) void*)(lds + 16384 + i * 4096 + wave * 1024),
          16, 0, 0);
    }
    __syncthreads();  // compiler drains vmcnt before barrier
#pragma unroll
    for (int ks = 0; ks < 2; ks++) {
      bf16x8 av[4], bv[4];
#pragma unroll
      for (int m = 0; m < 4; m++) {
        int row = wr * 64 + m * 16 + l16;
        int logical = row * 128 + ks * 64 + q * 16;
        av[m] = *(const bf16x8*)(lds + SWZ(logical));
      }
#pragma unroll
      for (int n = 0; n < 4; n++) {
        int row = wcid * 64 + n * 16 + l16;
        int logical = row * 128 + ks * 64 + q * 16;
        bv[n] = *(const bf16x8*)(lds + 16384 + SWZ(logical));
      }
#pragma unroll
      for (int m = 0; m < 4; m++)
#pragma unroll
        for (int n = 0; n < 4; n++)
          acc[m][n] = __builtin_amdgcn_mfma_f32_16x16x32_bf16(av[m], bv[n], acc[m][n], 0, 0, 0);
    }
    __syncthreads();
  }

  // epilogue: kv = exp(-gamma * max(f2 + p2 - 2*dot, 0))
  // C/D layout (16x16): col = lane&15, row = (lane>>4)*4 + j
  float p2v[4];
#pragma unroll
  for (int n = 0; n < 4; n++) p2v[n] = p2[bn * 128 + wcid * 64 + n * 16 + l16];
#pragma unroll
  for (int m = 0; m < 4; m++) {
#pragma unroll
    for (int j = 0; j < 4; j++) {
      int grow = bm * 128 + wr * 64 + m * 16 + q * 4 + j;
      float f2v = f2[grow];
      float* kvp = kv + (size_t)grow * 4096 + bn * 128 + wcid * 64 + l16;
#pragma unroll
      for (int n = 0; n < 4; n++) {
        float d2 = fmaxf(f2v + p2v[n] - 2.0f * acc[m][n][j], 0.f);
        kvp[n * 16] = __expf(-GAMMA * d2);
      }
    }
  }
}

// ---------------- Kernel 4: logits = kv @ head_w^T + b; log_softmax ----------------
__global__ __launch_bounds__(256) void head_ls_k(
    const float* __restrict__ kv, const float* __restrict__ hw,
    const float* __restrict__ hb, float* __restrict__ out) {
  const int b = blockIdx.x, tid = threadIdx.x;
  const float4* kvr = (const float4*)(kv + (size_t)b * 4096);
  float part[10];
#pragma unroll
  for (int c = 0; c < 10; c++) part[c] = 0.f;
#pragma unroll
  for (int k = 0; k < 4; k++) {
    int idx = tid + k * 256;
    float4 v = kvr[idx];
#pragma unroll
    for (int c = 0; c < 10; c++) {
      float4 w = *(const float4*)(hw + c * 4096 + idx * 4);
      part[c] += v.x * w.x + v.y * w.y + v.z * w.z + v.w * w.w;
    }
  }
#pragma unroll
  for (int c = 0; c < 10; c++)
    for (int off = 32; off > 0; off >>= 1) part[c] += __shfl_down(part[c], off);
  __shared__ float red[4][10];
  if ((tid & 63) == 0) {
#pragma unroll
    for (int c = 0; c < 10; c++) red[tid >> 6][c] = part[c];
  }
  __syncthreads();
  if (tid == 0) {
    float l[10], m = -1e30f;
#pragma unroll
    for (int c = 0; c < 10; c++) {
      l[c] = red[0][c] + red[1][c] + red[2][c] + red[3][c] + hb[c];
      m = fmaxf(m, l[c]);
    }
    float s = 0.f;
#pragma unroll
    for (int c = 0; c < 10; c++) s += __expf(l[c] - m);
    float lse = logf(s);
#pragma unroll
    for (int c = 0; c < 10; c++) out[(size_t)b * 10 + c] = l[c] - m - lse;
  }
}

extern "C" void kernel_launch(void* const* d_in, const int* in_sizes, int n_in,
                              void* d_out, int out_size, void* d_ws, size_t ws_size,
                              hipStream_t stream) {
  const float* x      = (const float*)d_in[0];
  const float* protos = (const float*)d_in[1];
  const float* conv_w = (const float*)d_in[2];
  const float* conv_b = (const float*)d_in[3];
  const float* head_w = (const float*)d_in[4];
  const float* head_b = (const float*)d_in[5];
  float* out = (float*)d_out;
  char* ws = (char*)d_ws;

  // workspace layout (total ~84 MB)
  __hip_bfloat16* pB = (__hip_bfloat16*)ws;                            // 4096x4096 bf16 = 32 MB
  __hip_bfloat16* fA = (__hip_bfloat16*)(ws + 33554432);               // 2048x4096 bf16 = 16 MB
  float* kv = (float*)(ws + 33554432 + 16777216);                      // 2048x4096 f32  = 32 MB
  float* f2 = (float*)(ws + 33554432 + 16777216 + 33554432);           // 2048 f32
  float* p2 = (float*)(ws + 33554432 + 16777216 + 33554432 + 8192);    // 4096 f32

  hipLaunchKernelGGL(conv_feats_k, dim3(2048), dim3(256), 0, stream, x, conv_w, conv_b, fA, f2);
  hipLaunchKernelGGL(proto_prep_k, dim3(4096), dim3(256), 0, stream, protos, pB, p2);
  hipLaunchKernelGGL(gemm_kv_k, dim3(32, 16), dim3(256), 0, stream, fA, pB, f2, p2, kv);
  hipLaunchKernelGGL(head_ls_k, dim3(2048), dim3(256), 0, stream, kv, head_w, head_b, out);
}

// Round 2
// 113.873 us; speedup vs baseline: 1.0593x; 1.0593x over previous
//
#include <hip/hip_runtime.h>
#include <hip/hip_bf16.h>
#include <stdint.h>

#define GAMMA 1e-4f

typedef __bf16 bf16x8 __attribute__((ext_vector_type(8)));
typedef float f32x4 __attribute__((ext_vector_type(4)));

__device__ __forceinline__ unsigned short f2bf(float f) {
  __hip_bfloat16 h = __float2bfloat16(f);
  unsigned short u;
  __builtin_memcpy(&u, &h, 2);
  return u;
}
__device__ __forceinline__ float bf2f(unsigned short u) {
  unsigned int x = ((unsigned int)u) << 16;
  float f; __builtin_memcpy(&f, &x, 4);
  return f;
}

// ---------------- Kernel 1: merged prep ----------------
// blocks [0,4096): prototypes -> bf16 + ||p||^2
// blocks [4096,6144): 2x2 stride-2 conv -> bf16 feats + ||f||^2
__global__ __launch_bounds__(256) void prep_k(
    const float* __restrict__ x, const float* __restrict__ cw,
    const float* __restrict__ cb, __hip_bfloat16* __restrict__ feats,
    float* __restrict__ f2, const float* __restrict__ pr,
    __hip_bfloat16* __restrict__ pb, float* __restrict__ p2) {
  const int tid = threadIdx.x;
  __shared__ float red[4];
  if (blockIdx.x < 4096) {
    const int j = blockIdx.x;
    const float4* src = (const float4*)(pr + (size_t)j * 4096);
    ushort4* dst = (ushort4*)(pb + (size_t)j * 4096);
    float ssq = 0.f;
#pragma unroll
    for (int k = 0; k < 4; k++) {
      float4 v = src[tid + k * 256];
      ssq += v.x * v.x + v.y * v.y + v.z * v.z + v.w * v.w;
      ushort4 u;
      u.x = f2bf(v.x); u.y = f2bf(v.y); u.z = f2bf(v.z); u.w = f2bf(v.w);
      dst[tid + k * 256] = u;
    }
    for (int off = 32; off > 0; off >>= 1) ssq += __shfl_down(ssq, off);
    if ((tid & 63) == 0) red[tid >> 6] = ssq;
    __syncthreads();
    if (tid == 0) p2[j] = red[0] + red[1] + red[2] + red[3];
  } else {
    const int b = blockIdx.x - 4096;
    __shared__ float swb[20];
    if (tid < 16) swb[tid] = cw[tid];
    else if (tid < 20) swb[tid] = cb[tid - 16];
    __syncthreads();
    float w[16], bias[4];
#pragma unroll
    for (int i = 0; i < 16; i++) w[i] = swb[i];
#pragma unroll
    for (int c = 0; c < 4; c++) bias[c] = swb[16 + c];
    const float* xb = x + (size_t)b * 4096;
    __hip_bfloat16* fb = feats + (size_t)b * 4096;
    float ssq = 0.f;
#pragma unroll
    for (int k = 0; k < 4; k++) {
      int p = tid + k * 256;         // output position 0..1023
      int h = p >> 5, wcol = p & 31;
      float2 t0 = *(const float2*)(xb + (2 * h) * 64 + 2 * wcol);
      float2 t1 = *(const float2*)(xb + (2 * h + 1) * 64 + 2 * wcol);
#pragma unroll
      for (int c = 0; c < 4; c++) {
        float v = bias[c] + t0.x * w[c * 4 + 0] + t0.y * w[c * 4 + 1]
                          + t1.x * w[c * 4 + 2] + t1.y * w[c * 4 + 3];
        fb[c * 1024 + p] = __float2bfloat16(v);
        ssq += v * v;
      }
    }
    for (int off = 32; off > 0; off >>= 1) ssq += __shfl_down(ssq, off);
    if ((tid & 63) == 0) red[tid >> 6] = ssq;
    __syncthreads();
    if (tid == 0) f2[b] = red[0] + red[1] + red[2] + red[3];
  }
}

// ---------------- Kernel 2: bf16 GEMM (feats x protos^T) + RBF epilogue ----------------
// BM=128, BN=256, BK=64; 8 waves (2M x 4N); 3-deep LDS ring (tiles t,t+1,t+2);
// counted s_waitcnt vmcnt(12) — never drains to 0 in the main loop (T3+T4);
// setprio around MFMA clusters (T5); both-sides XOR swizzle (T2, rule #21).
#define SWZ(o) ((o) ^ ((((o) >> 7) & 7) << 4))
#define TILE_BYTES 49152   // A 16384 + B 32768

__global__ __launch_bounds__(512, 2) void gemm_kv_k(
    const __hip_bfloat16* __restrict__ A, const __hip_bfloat16* __restrict__ B,
    const float* __restrict__ f2, const float* __restrict__ p2,
    __hip_bfloat16* __restrict__ kv) {
  __shared__ __align__(16) char lds[3 * TILE_BYTES];  // 144 KiB
  const int tid = threadIdx.x;
  const int wave = tid >> 6, lane = tid & 63;
  const int q = lane >> 4, l16 = lane & 15;
  const int wr = wave >> 2, wc = wave & 3;

  // XCD-aware tile swizzle: 256 WGs = 8 XCDs x 32; each XCD gets an 8(bm) x 4(bn) patch.
  const int wg = blockIdx.x;
  const int xcd = wg & 7, loc = wg >> 3;
  const int bm = (xcd & 1) * 8 + (loc & 7);
  const int bn = (xcd >> 1) * 4 + (loc >> 3);

  // staging: linear LDS dest, pre-swizzled global src (rule #21)
  const __hip_bfloat16* agp[2];
  const __hip_bfloat16* bgp[4];
  int aoff[2], boff[4];
#pragma unroll
  for (int i = 0; i < 2; i++) {
    int loff = (i * 512 + tid) * 16;
    aoff[i] = loff;
    int lg = SWZ(loff);
    agp[i] = A + (size_t)(bm * 128 + (lg >> 7)) * 4096 + ((lg & 127) >> 1);
  }
#pragma unroll
  for (int i = 0; i < 4; i++) {
    int loff = (i * 512 + tid) * 16;
    boff[i] = loff;
    int lg = SWZ(loff);
    bgp[i] = B + (size_t)(bn * 256 + (lg >> 7)) * 4096 + ((lg & 127) >> 1);
  }

  auto STAGE = [&](int kt, char* base) {
#pragma unroll
    for (int i = 0; i < 2; i++)
      __builtin_amdgcn_global_load_lds(
          (__attribute__((address_space(1))) void*)(void*)(agp[i] + kt * 64),
          (__attribute__((address_space(3))) void*)(base + aoff[i]), 16, 0, 0);
#pragma unroll
    for (int i = 0; i < 4; i++)
      __builtin_amdgcn_global_load_lds(
          (__attribute__((address_space(1))) void*)(void*)(bgp[i] + kt * 64),
          (__attribute__((address_space(3))) void*)(base + 16384 + boff[i]), 16, 0, 0);
  };

  f32x4 acc[4][4] = {};

  char* pt0 = lds;                  // tile t
  char* pt1 = lds + TILE_BYTES;     // tile t+1
  char* pt2 = lds + 2 * TILE_BYTES; // tile t+2 (being staged)

  STAGE(0, pt0);
  STAGE(1, pt1);

  for (int t = 0; t < 64; ++t) {
    // issue next-next tile (wrap at the tail: extra loads land in dead buffers)
    STAGE((t + 2) & 63, pt2);
    __builtin_amdgcn_sched_barrier(0);
    asm volatile("s_waitcnt vmcnt(12)" ::: "memory");  // tile t landed; t+1,t+2 in flight
    __builtin_amdgcn_sched_barrier(0);
    __builtin_amdgcn_s_barrier();

#pragma unroll
    for (int ks = 0; ks < 2; ks++) {
      bf16x8 av[4], bv[4];
#pragma unroll
      for (int m = 0; m < 4; m++) {
        int lg = (wr * 64 + m * 16 + l16) * 128 + ks * 64 + q * 16;
        av[m] = *(const bf16x8*)(pt0 + SWZ(lg));
      }
#pragma unroll
      for (int n = 0; n < 4; n++) {
        int lg = (wc * 64 + n * 16 + l16) * 128 + ks * 64 + q * 16;
        bv[n] = *(const bf16x8*)(pt0 + 16384 + SWZ(lg));
      }
      __builtin_amdgcn_s_setprio(1);
#pragma unroll
      for (int m = 0; m < 4; m++)
#pragma unroll
        for (int n = 0; n < 4; n++)
          acc[m][n] = __builtin_amdgcn_mfma_f32_16x16x32_bf16(av[m], bv[n], acc[m][n], 0, 0, 0);
      __builtin_amdgcn_s_setprio(0);
    }

    __builtin_amdgcn_sched_barrier(0);
    __builtin_amdgcn_s_barrier();   // all waves done reading buf t
    char* tmp = pt0; pt0 = pt1; pt1 = pt2; pt2 = tmp;
  }

  // drain outstanding LDS-bound loads before kernel end / epilogue
  asm volatile("s_waitcnt vmcnt(0)" ::: "memory");

  // epilogue: kv = bf16(exp(-gamma * max(f2 + p2 - 2*dot, 0)))
  // C/D layout (16x16): col = lane&15, row = (lane>>4)*4 + j
  float p2v[4];
#pragma unroll
  for (int n = 0; n < 4; n++) p2v[n] = p2[bn * 256 + wc * 64 + n * 16 + l16];
#pragma unroll
  for (int m = 0; m < 4; m++) {
#pragma unroll
    for (int j = 0; j < 4; j++) {
      int grow = bm * 128 + wr * 64 + m * 16 + q * 4 + j;
      float f2v = f2[grow];
      __hip_bfloat16* kvp = kv + (size_t)grow * 4096 + bn * 256 + wc * 64 + l16;
#pragma unroll
      for (int n = 0; n < 4; n++) {
        float d2 = fmaxf(f2v + p2v[n] - 2.0f * acc[m][n][j], 0.f);
        kvp[n * 16] = __float2bfloat16(__expf(-GAMMA * d2));
      }
    }
  }
}

// ---------------- Kernel 3: logits = kv @ head_w^T + b; log_softmax ----------------
__global__ __launch_bounds__(256) void head_ls_k(
    const __hip_bfloat16* __restrict__ kv, const float* __restrict__ hw,
    const float* __restrict__ hb, float* __restrict__ out) {
  const int b = blockIdx.x, tid = threadIdx.x;
  const ushort4* kvr = (const ushort4*)(kv + (size_t)b * 4096);
  float part[10];
#pragma unroll
  for (int c = 0; c < 10; c++) part[c] = 0.f;
#pragma unroll
  for (int k = 0; k < 4; k++) {
    int idx = tid + k * 256;          // ushort4 chunk index, 0..1023
    ushort4 v = kvr[idx];
    float a0 = bf2f(v.x), a1 = bf2f(v.y), a2 = bf2f(v.z), a3 = bf2f(v.w);
#pragma unroll
    for (int c = 0; c < 10; c++) {
      float4 w = *(const float4*)(hw + c * 4096 + idx * 4);
      part[c] += a0 * w.x + a1 * w.y + a2 * w.z + a3 * w.w;
    }
  }
#pragma unroll
  for (int c = 0; c < 10; c++)
    for (int off = 32; off > 0; off >>= 1) part[c] += __shfl_down(part[c], off);
  __shared__ float red[4][10];
  if ((tid & 63) == 0) {
#pragma unroll
    for (int c = 0; c < 10; c++) red[tid >> 6][c] = part[c];
  }
  __syncthreads();
  if (tid == 0) {
    float l[10], m = -1e30f;
#pragma unroll
    for (int c = 0; c < 10; c++) {
      l[c] = red[0][c] + red[1][c] + red[2][c] + red[3][c] + hb[c];
      m = fmaxf(m, l[c]);
    }
    float s = 0.f;
#pragma unroll
    for (int c = 0; c < 10; c++) s += __expf(l[c] - m);
    float lse = logf(s);
#pragma unroll
    for (int c = 0; c < 10; c++) out[(size_t)b * 10 + c] = l[c] - m - lse;
  }
}

extern "C" void kernel_launch(void* const* d_in, const int* in_sizes, int n_in,
                              void* d_out, int out_size, void* d_ws, size_t ws_size,
                              hipStream_t stream) {
  const float* x      = (const float*)d_in[0];
  const float* protos = (const float*)d_in[1];
  const float* conv_w = (const float*)d_in[2];
  const float* conv_b = (const float*)d_in[3];
  const float* head_w = (const float*)d_in[4];
  const float* head_b = (const float*)d_in[5];
  float* out = (float*)d_out;
  char* ws = (char*)d_ws;

  // workspace layout (~64 MB)
  __hip_bfloat16* pB  = (__hip_bfloat16*)ws;                     // 4096x4096 bf16 = 32 MB
  __hip_bfloat16* fA  = (__hip_bfloat16*)(ws + (32u << 20));     // 2048x4096 bf16 = 16 MB
  __hip_bfloat16* kvb = (__hip_bfloat16*)(ws + (48u << 20));     // 2048x4096 bf16 = 16 MB
  float* f2 = (float*)(ws + (64u << 20));                        // 2048 f32
  float* p2 = (float*)(ws + (64u << 20) + 8192);                 // 4096 f32

  hipLaunchKernelGGL(prep_k, dim3(6144), dim3(256), 0, stream,
                     x, conv_w, conv_b, fA, f2, protos, pB, p2);
  hipLaunchKernelGGL(gemm_kv_k, dim3(256), dim3(512), 0, stream, fA, pB, f2, p2, kvb);
  hipLaunchKernelGGL(head_ls_k, dim3(2048), dim3(256), 0, stream, kvb, head_w, head_b, out);
}

// Round 3
// 107.099 us; speedup vs baseline: 1.1263x; 1.0633x over previous
//
#include <hip/hip_runtime.h>
#include <hip/hip_bf16.h>
#include <stdint.h>

#define GAMMA 1e-4f

typedef __bf16 bf16x8 __attribute__((ext_vector_type(8)));
typedef float f32x4 __attribute__((ext_vector_type(4)));

__device__ __forceinline__ unsigned short f2bf(float f) {
  __hip_bfloat16 h = __float2bfloat16(f);
  unsigned short u;
  __builtin_memcpy(&u, &h, 2);
  return u;
}
__device__ __forceinline__ float bf2f(unsigned short u) {
  unsigned int x = ((unsigned int)u) << 16;
  float f; __builtin_memcpy(&f, &x, 4);
  return f;
}

// ---------------- Kernel 1: merged prep ----------------
__global__ __launch_bounds__(256) void prep_k(
    const float* __restrict__ x, const float* __restrict__ cw,
    const float* __restrict__ cb, __hip_bfloat16* __restrict__ feats,
    float* __restrict__ f2, const float* __restrict__ pr,
    __hip_bfloat16* __restrict__ pb, float* __restrict__ p2) {
  const int tid = threadIdx.x;
  __shared__ float red[4];
  if (blockIdx.x < 4096) {
    const int j = blockIdx.x;
    const float4* src = (const float4*)(pr + (size_t)j * 4096);
    ushort4* dst = (ushort4*)(pb + (size_t)j * 4096);
    float ssq = 0.f;
#pragma unroll
    for (int k = 0; k < 4; k++) {
      float4 v = src[tid + k * 256];
      ssq += v.x * v.x + v.y * v.y + v.z * v.z + v.w * v.w;
      ushort4 u;
      u.x = f2bf(v.x); u.y = f2bf(v.y); u.z = f2bf(v.z); u.w = f2bf(v.w);
      dst[tid + k * 256] = u;
    }
    for (int off = 32; off > 0; off >>= 1) ssq += __shfl_down(ssq, off);
    if ((tid & 63) == 0) red[tid >> 6] = ssq;
    __syncthreads();
    if (tid == 0) p2[j] = red[0] + red[1] + red[2] + red[3];
  } else {
    const int b = blockIdx.x - 4096;
    __shared__ float swb[20];
    if (tid < 16) swb[tid] = cw[tid];
    else if (tid < 20) swb[tid] = cb[tid - 16];
    __syncthreads();
    float w[16], bias[4];
#pragma unroll
    for (int i = 0; i < 16; i++) w[i] = swb[i];
#pragma unroll
    for (int c = 0; c < 4; c++) bias[c] = swb[16 + c];
    const float* xb = x + (size_t)b * 4096;
    __hip_bfloat16* fb = feats + (size_t)b * 4096;
    float ssq = 0.f;
#pragma unroll
    for (int k = 0; k < 4; k++) {
      int p = tid + k * 256;
      int h = p >> 5, wcol = p & 31;
      float2 t0 = *(const float2*)(xb + (2 * h) * 64 + 2 * wcol);
      float2 t1 = *(const float2*)(xb + (2 * h + 1) * 64 + 2 * wcol);
#pragma unroll
      for (int c = 0; c < 4; c++) {
        float v = bias[c] + t0.x * w[c * 4 + 0] + t0.y * w[c * 4 + 1]
                          + t1.x * w[c * 4 + 2] + t1.y * w[c * 4 + 3];
        fb[c * 1024 + p] = __float2bfloat16(v);
        ssq += v * v;
      }
    }
    for (int off = 32; off > 0; off >>= 1) ssq += __shfl_down(ssq, off);
    if ((tid & 63) == 0) red[tid >> 6] = ssq;
    __syncthreads();
    if (tid == 0) f2[b] = red[0] + red[1] + red[2] + red[3];
  }
}

// ---------------- Kernel 2: bf16 GEMM + RBF epilogue, fine-phase schedule ----------------
// BM=128, BN=256, BK=64; 8 waves (2M x 4N); 3-deep LDS ring; 2 fine phases per K-tile:
// {8 ds_read || 3 global_load_lds -> barrier -> lgkmcnt(0) -> 16 MFMA -> barrier};
// vmcnt(6) once per K-tile BEFORE the trailing barrier (T3+T4); setprio (T5); XOR swizzle (T2).
#define SWZ(o) ((o) ^ ((((o) >> 7) & 7) << 4))
#define TILE_BYTES 49152

#define GLDS(gsrc, ldst)                                                    \
  __builtin_amdgcn_global_load_lds(                                         \
      (__attribute__((address_space(1))) void*)(void*)(gsrc),               \
      (__attribute__((address_space(3))) void*)(ldst), 16, 0, 0)

__global__ __launch_bounds__(512, 1) void gemm_kv_k(
    const __hip_bfloat16* __restrict__ A, const __hip_bfloat16* __restrict__ B,
    const float* __restrict__ f2, const float* __restrict__ p2,
    __hip_bfloat16* __restrict__ kv) {
  __shared__ __align__(16) char lds[3 * TILE_BYTES];  // 144 KiB
  const int tid = threadIdx.x;
  const int wave = tid >> 6, lane = tid & 63;
  const int q = lane >> 4, l16 = lane & 15;
  const int wr = wave >> 2, wc = wave & 3;

  // XCD-aware tile swizzle: 256 WGs = 8 XCDs x 32
  const int wg = blockIdx.x;
  const int xcd = wg & 7, loc = wg >> 3;
  const int bm = (xcd & 1) * 8 + (loc & 7);
  const int bn = (xcd >> 1) * 4 + (loc >> 3);

  // staging: linear LDS dest, pre-swizzled global src (rule #21)
  const __hip_bfloat16* agp[2];
  const __hip_bfloat16* bgp[4];
  int aoff[2], boff[4];
#pragma unroll
  for (int i = 0; i < 2; i++) {
    int loff = (i * 512 + tid) * 16;
    aoff[i] = loff;
    int lg = SWZ(loff);
    agp[i] = A + (size_t)(bm * 128 + (lg >> 7)) * 4096 + ((lg & 127) >> 1);
  }
#pragma unroll
  for (int i = 0; i < 4; i++) {
    int loff = (i * 512 + tid) * 16;
    boff[i] = loff;
    int lg = SWZ(loff);
    bgp[i] = B + (size_t)(bn * 256 + (lg >> 7)) * 4096 + ((lg & 127) >> 1);
  }

  f32x4 acc[4][4] = {};

  char* pt0 = lds;                   // tile t
  char* pt1 = lds + TILE_BYTES;      // tile t+1
  char* pt2 = lds + 2 * TILE_BYTES;  // tile t+2 (staging target)

  // prologue: stage tiles 0 and 1
#pragma unroll
  for (int i = 0; i < 2; i++) GLDS(agp[i], pt0 + aoff[i]);
#pragma unroll
  for (int i = 0; i < 4; i++) GLDS(bgp[i], pt0 + 16384 + boff[i]);
#pragma unroll
  for (int i = 0; i < 2; i++) GLDS(agp[i] + 64, pt1 + aoff[i]);
#pragma unroll
  for (int i = 0; i < 4; i++) GLDS(bgp[i] + 64, pt1 + 16384 + boff[i]);
  asm volatile("s_waitcnt vmcnt(6)" ::: "memory");  // tile 0 landed
  __builtin_amdgcn_s_barrier();

#pragma unroll 1
  for (int t = 0; t < 64; ++t) {
    const int kt2 = ((t + 2) & 63) * 64;  // staged K-offset (wraps to dead writes at tail)

    // ================= phase 0 (ks = 0) =================
    {
      bf16x8 av[4], bv[4];
#pragma unroll
      for (int m = 0; m < 4; m++)
        av[m] = *(const bf16x8*)(pt0 + SWZ((wr * 64 + m * 16 + l16) * 128 + q * 16));
#pragma unroll
      for (int n = 0; n < 4; n++)
        bv[n] = *(const bf16x8*)(pt0 + 16384 + SWZ((wc * 64 + n * 16 + l16) * 128 + q * 16));
      GLDS(agp[0] + kt2, pt2 + aoff[0]);
      GLDS(agp[1] + kt2, pt2 + aoff[1]);
      GLDS(bgp[0] + kt2, pt2 + 16384 + boff[0]);
      __builtin_amdgcn_sched_barrier(0);
      __builtin_amdgcn_s_barrier();
      asm volatile("s_waitcnt lgkmcnt(0)" ::: "memory");
      __builtin_amdgcn_sched_barrier(0);
      __builtin_amdgcn_s_setprio(1);
#pragma unroll
      for (int m = 0; m < 4; m++)
#pragma unroll
        for (int n = 0; n < 4; n++)
          acc[m][n] = __builtin_amdgcn_mfma_f32_16x16x32_bf16(av[m], bv[n], acc[m][n], 0, 0, 0);
      __builtin_amdgcn_s_setprio(0);
      __builtin_amdgcn_sched_barrier(0);
      __builtin_amdgcn_s_barrier();
    }

    // ================= phase 1 (ks = 1) =================
    {
      bf16x8 av[4], bv[4];
#pragma unroll
      for (int m = 0; m < 4; m++)
        av[m] = *(const bf16x8*)(pt0 + SWZ((wr * 64 + m * 16 + l16) * 128 + 64 + q * 16));
#pragma unroll
      for (int n = 0; n < 4; n++)
        bv[n] = *(const bf16x8*)(pt0 + 16384 + SWZ((wc * 64 + n * 16 + l16) * 128 + 64 + q * 16));
      GLDS(bgp[1] + kt2, pt2 + 16384 + boff[1]);
      GLDS(bgp[2] + kt2, pt2 + 16384 + boff[2]);
      GLDS(bgp[3] + kt2, pt2 + 16384 + boff[3]);
      __builtin_amdgcn_sched_barrier(0);
      __builtin_amdgcn_s_barrier();
      asm volatile("s_waitcnt lgkmcnt(0)" ::: "memory");
      __builtin_amdgcn_sched_barrier(0);
      __builtin_amdgcn_s_setprio(1);
#pragma unroll
      for (int m = 0; m < 4; m++)
#pragma unroll
        for (int n = 0; n < 4; n++)
          acc[m][n] = __builtin_amdgcn_mfma_f32_16x16x32_bf16(av[m], bv[n], acc[m][n], 0, 0, 0);
      __builtin_amdgcn_s_setprio(0);
      // tile t+1 must be fully landed before anyone reads it next iter:
      asm volatile("s_waitcnt vmcnt(6)" ::: "memory");  // t+2's 6 loads may stay in flight
      __builtin_amdgcn_sched_barrier(0);
      __builtin_amdgcn_s_barrier();
    }

    char* tmp = pt0; pt0 = pt1; pt1 = pt2; pt2 = tmp;
  }

  asm volatile("s_waitcnt vmcnt(0)" ::: "memory");  // drain dead tail stages

  // epilogue: kv = bf16(exp(-gamma * max(f2 + p2 - 2*dot, 0)))
  float p2v[4];
#pragma unroll
  for (int n = 0; n < 4; n++) p2v[n] = p2[bn * 256 + wc * 64 + n * 16 + l16];
#pragma unroll
  for (int m = 0; m < 4; m++) {
#pragma unroll
    for (int j = 0; j < 4; j++) {
      int grow = bm * 128 + wr * 64 + m * 16 + q * 4 + j;
      float f2v = f2[grow];
      __hip_bfloat16* kvp = kv + (size_t)grow * 4096 + bn * 256 + wc * 64 + l16;
#pragma unroll
      for (int n = 0; n < 4; n++) {
        float d2 = fmaxf(f2v + p2v[n] - 2.0f * acc[m][n][j], 0.f);
        kvp[n * 16] = __float2bfloat16(__expf(-GAMMA * d2));
      }
    }
  }
}

// ---------------- Kernel 3: logits = kv @ head_w^T + b; log_softmax ----------------
__global__ __launch_bounds__(256) void head_ls_k(
    const __hip_bfloat16* __restrict__ kv, const float* __restrict__ hw,
    const float* __restrict__ hb, float* __restrict__ out) {
  const int b = blockIdx.x, tid = threadIdx.x;
  const ushort4* kvr = (const ushort4*)(kv + (size_t)b * 4096);
  float part[10];
#pragma unroll
  for (int c = 0; c < 10; c++) part[c] = 0.f;
#pragma unroll
  for (int k = 0; k < 4; k++) {
    int idx = tid + k * 256;
    ushort4 v = kvr[idx];
    float a0 = bf2f(v.x), a1 = bf2f(v.y), a2 = bf2f(v.z), a3 = bf2f(v.w);
#pragma unroll
    for (int c = 0; c < 10; c++) {
      float4 w = *(const float4*)(hw + c * 4096 + idx * 4);
      part[c] += a0 * w.x + a1 * w.y + a2 * w.z + a3 * w.w;
    }
  }
#pragma unroll
  for (int c = 0; c < 10; c++)
    for (int off = 32; off > 0; off >>= 1) part[c] += __shfl_down(part[c], off);
  __shared__ float red[4][10];
  if ((tid & 63) == 0) {
#pragma unroll
    for (int c = 0; c < 10; c++) red[tid >> 6][c] = part[c];
  }
  __syncthreads();
  if (tid == 0) {
    float l[10], m = -1e30f;
#pragma unroll
    for (int c = 0; c < 10; c++) {
      l[c] = red[0][c] + red[1][c] + red[2][c] + red[3][c] + hb[c];
      m = fmaxf(m, l[c]);
    }
    float s = 0.f;
#pragma unroll
    for (int c = 0; c < 10; c++) s += __expf(l[c] - m);
    float lse = logf(s);
#pragma unroll
    for (int c = 0; c < 10; c++) out[(size_t)b * 10 + c] = l[c] - m - lse;
  }
}

extern "C" void kernel_launch(void* const* d_in, const int* in_sizes, int n_in,
                              void* d_out, int out_size, void* d_ws, size_t ws_size,
                              hipStream_t stream) {
  const float* x      = (const float*)d_in[0];
  const float* protos = (const float*)d_in[1];
  const float* conv_w = (const float*)d_in[2];
  const float* conv_b = (const float*)d_in[3];
  const float* head_w = (const float*)d_in[4];
  const float* head_b = (const float*)d_in[5];
  float* out = (float*)d_out;
  char* ws = (char*)d_ws;

  __hip_bfloat16* pB  = (__hip_bfloat16*)ws;                     // 4096x4096 bf16 = 32 MB
  __hip_bfloat16* fA  = (__hip_bfloat16*)(ws + (32u << 20));     // 2048x4096 bf16 = 16 MB
  __hip_bfloat16* kvb = (__hip_bfloat16*)(ws + (48u << 20));     // 2048x4096 bf16 = 16 MB
  float* f2 = (float*)(ws + (64u << 20));                        // 2048 f32
  float* p2 = (float*)(ws + (64u << 20) + 8192);                 // 4096 f32

  hipLaunchKernelGGL(prep_k, dim3(6144), dim3(256), 0, stream,
                     x, conv_w, conv_b, fA, f2, protos, pB, p2);
  hipLaunchKernelGGL(gemm_kv_k, dim3(256), dim3(512), 0, stream, fA, pB, f2, p2, kvb);
  hipLaunchKernelGGL(head_ls_k, dim3(2048), dim3(256), 0, stream, kvb, head_w, head_b, out);
}

// Round 4
// 104.815 us; speedup vs baseline: 1.1508x; 1.0218x over previous
//
#include <hip/hip_runtime.h>
#include <hip/hip_bf16.h>
#include <stdint.h>

#define GAMMA 1e-4f

typedef __bf16 bf16x8 __attribute__((ext_vector_type(8)));
typedef float f32x4 __attribute__((ext_vector_type(4)));

__device__ __forceinline__ unsigned short f2bf(float f) {
  __hip_bfloat16 h = __float2bfloat16(f);
  unsigned short u;
  __builtin_memcpy(&u, &h, 2);
  return u;
}
__device__ __forceinline__ float bf2f(unsigned short u) {
  unsigned int x = ((unsigned int)u) << 16;
  float f; __builtin_memcpy(&f, &x, 4);
  return f;
}

// ---------------- Kernel 1: merged prep ----------------
__global__ __launch_bounds__(256) void prep_k(
    const float* __restrict__ x, const float* __restrict__ cw,
    const float* __restrict__ cb, __hip_bfloat16* __restrict__ feats,
    float* __restrict__ f2, const float* __restrict__ pr,
    __hip_bfloat16* __restrict__ pb, float* __restrict__ p2) {
  const int tid = threadIdx.x;
  __shared__ float red[4];
  if (blockIdx.x < 4096) {
    const int j = blockIdx.x;
    const float4* src = (const float4*)(pr + (size_t)j * 4096);
    ushort4* dst = (ushort4*)(pb + (size_t)j * 4096);
    float ssq = 0.f;
#pragma unroll
    for (int k = 0; k < 4; k++) {
      float4 v = src[tid + k * 256];
      ssq += v.x * v.x + v.y * v.y + v.z * v.z + v.w * v.w;
      ushort4 u;
      u.x = f2bf(v.x); u.y = f2bf(v.y); u.z = f2bf(v.z); u.w = f2bf(v.w);
      dst[tid + k * 256] = u;
    }
    for (int off = 32; off > 0; off >>= 1) ssq += __shfl_down(ssq, off);
    if ((tid & 63) == 0) red[tid >> 6] = ssq;
    __syncthreads();
    if (tid == 0) p2[j] = red[0] + red[1] + red[2] + red[3];
  } else {
    const int b = blockIdx.x - 4096;
    __shared__ float swb[20];
    if (tid < 16) swb[tid] = cw[tid];
    else if (tid < 20) swb[tid] = cb[tid - 16];
    __syncthreads();
    float w[16], bias[4];
#pragma unroll
    for (int i = 0; i < 16; i++) w[i] = swb[i];
#pragma unroll
    for (int c = 0; c < 4; c++) bias[c] = swb[16 + c];
    const float* xb = x + (size_t)b * 4096;
    __hip_bfloat16* fb = feats + (size_t)b * 4096;
    float ssq = 0.f;
#pragma unroll
    for (int k = 0; k < 4; k++) {
      int p = tid + k * 256;
      int h = p >> 5, wcol = p & 31;
      float2 t0 = *(const float2*)(xb + (2 * h) * 64 + 2 * wcol);
      float2 t1 = *(const float2*)(xb + (2 * h + 1) * 64 + 2 * wcol);
#pragma unroll
      for (int c = 0; c < 4; c++) {
        float v = bias[c] + t0.x * w[c * 4 + 0] + t0.y * w[c * 4 + 1]
                          + t1.x * w[c * 4 + 2] + t1.y * w[c * 4 + 3];
        fb[c * 1024 + p] = __float2bfloat16(v);
        ssq += v * v;
      }
    }
    for (int off = 32; off > 0; off >>= 1) ssq += __shfl_down(ssq, off);
    if ((tid & 63) == 0) red[tid >> 6] = ssq;
    __syncthreads();
    if (tid == 0) f2[b] = red[0] + red[1] + red[2] + red[3];
  }
}

// ---------------- Kernel 2: bf16 GEMM + RBF epilogue ----------------
// BM=128, BN=256, BK=64; 8 waves (2M x 4N); 3-deep LDS ring.
// ONE barrier per K-tile + register read-ahead + counted lgkmcnt:
// {ph0 reads | 3 GLDS | ph1 reads | 3 GLDS | lgkmcnt(8) | MFMA ph0 |
//  lgkmcnt(0) | MFMA ph1 | vmcnt(6) | s_barrier}.
#define SWZ(o) ((o) ^ ((((o) >> 7) & 7) << 4))
#define TILE_BYTES 49152

#define GLDS(gsrc, ldst)                                                    \
  __builtin_amdgcn_global_load_lds(                                         \
      (__attribute__((address_space(1))) void*)(void*)(gsrc),               \
      (__attribute__((address_space(3))) void*)(ldst), 16, 0, 0)

__global__ __launch_bounds__(512, 1) void gemm_kv_k(
    const __hip_bfloat16* __restrict__ A, const __hip_bfloat16* __restrict__ B,
    const float* __restrict__ f2, const float* __restrict__ p2,
    __hip_bfloat16* __restrict__ kv) {
  __shared__ __align__(16) char lds[3 * TILE_BYTES];  // 144 KiB
  const int tid = threadIdx.x;
  const int wave = tid >> 6, lane = tid & 63;
  const int q = lane >> 4, l16 = lane & 15;
  const int wr = wave >> 2, wc = wave & 3;

  // XCD-aware tile swizzle: 256 WGs = 8 XCDs x 32
  const int wg = blockIdx.x;
  const int xcd = wg & 7, loc = wg >> 3;
  const int bm = (xcd & 1) * 8 + (loc & 7);
  const int bn = (xcd >> 1) * 4 + (loc >> 3);

  // staging: linear LDS dest, pre-swizzled global src (rule #21)
  const __hip_bfloat16* agp[2];
  const __hip_bfloat16* bgp[4];
  int aoff[2], boff[4];
#pragma unroll
  for (int i = 0; i < 2; i++) {
    int loff = (i * 512 + tid) * 16;
    aoff[i] = loff;
    int lg = SWZ(loff);
    agp[i] = A + (size_t)(bm * 128 + (lg >> 7)) * 4096 + ((lg & 127) >> 1);
  }
#pragma unroll
  for (int i = 0; i < 4; i++) {
    int loff = (i * 512 + tid) * 16;
    boff[i] = loff;
    int lg = SWZ(loff);
    bgp[i] = B + (size_t)(bn * 256 + (lg >> 7)) * 4096 + ((lg & 127) >> 1);
  }

  // precomputed swizzled fragment read offsets (LDS byte offsets)
  int ar[4], br[4];
#pragma unroll
  for (int m = 0; m < 4; m++)
    ar[m] = SWZ((wr * 64 + m * 16 + l16) * 128 + q * 16);
#pragma unroll
  for (int n = 0; n < 4; n++)
    br[n] = 16384 + SWZ((wc * 64 + n * 16 + l16) * 128 + q * 16);
  // ph1 offsets: +64 bytes in k -> SWZ leaves bit6 unchanged (XOR uses bit4 only
  // keyed on row bits >=7), so ph1 offset = ph0 offset + 64 always:
  // SWZ(x+64) = (x+64)^(((x+64)>>7&7)<<4); adding 64 can carry into bit7!
  // -> compute ph1 offsets independently below instead of assuming +64.
  int ar1[4], br1[4];
#pragma unroll
  for (int m = 0; m < 4; m++)
    ar1[m] = SWZ((wr * 64 + m * 16 + l16) * 128 + 64 + q * 16);
#pragma unroll
  for (int n = 0; n < 4; n++)
    br1[n] = 16384 + SWZ((wc * 64 + n * 16 + l16) * 128 + 64 + q * 16);

  f32x4 acc[4][4] = {};

  char* pt0 = lds;                   // tile t
  char* pt1 = lds + TILE_BYTES;      // tile t+1
  char* pt2 = lds + 2 * TILE_BYTES;  // tile t+2 (staging target)

  // prologue: stage tiles 0 and 1
#pragma unroll
  for (int i = 0; i < 2; i++) GLDS(agp[i], pt0 + aoff[i]);
#pragma unroll
  for (int i = 0; i < 4; i++) GLDS(bgp[i], pt0 + 16384 + boff[i]);
#pragma unroll
  for (int i = 0; i < 2; i++) GLDS(agp[i] + 64, pt1 + aoff[i]);
#pragma unroll
  for (int i = 0; i < 4; i++) GLDS(bgp[i] + 64, pt1 + 16384 + boff[i]);
  asm volatile("s_waitcnt vmcnt(6)" ::: "memory");  // own tile-0 loads landed
  __builtin_amdgcn_s_barrier();                     // -> all tile-0 loads landed

#pragma unroll 1
  for (int t = 0; t < 64; ++t) {
    const int kt2 = ((t + 2) & 63) * 64;  // staged K-offset (tail wraps -> dead writes)
    bf16x8 a0[4], b0[4], a1[4], b1[4];

    // ---- read group 0 (ph0 fragments, tile t) ----
    __builtin_amdgcn_sched_barrier(0);
#pragma unroll
    for (int m = 0; m < 4; m++) a0[m] = *(const bf16x8*)(pt0 + ar[m]);
#pragma unroll
    for (int n = 0; n < 4; n++) b0[n] = *(const bf16x8*)(pt0 + br[n]);
    __builtin_amdgcn_sched_barrier(0);
    // ---- stage first half of tile t+2 ----
    GLDS(agp[0] + kt2, pt2 + aoff[0]);
    GLDS(agp[1] + kt2, pt2 + aoff[1]);
    GLDS(bgp[0] + kt2, pt2 + 16384 + boff[0]);
    // ---- read group 1 (ph1 fragments, tile t) ----
#pragma unroll
    for (int m = 0; m < 4; m++) a1[m] = *(const bf16x8*)(pt0 + ar1[m]);
#pragma unroll
    for (int n = 0; n < 4; n++) b1[n] = *(const bf16x8*)(pt0 + br1[n]);
    // ---- stage second half of tile t+2 ----
    GLDS(bgp[1] + kt2, pt2 + 16384 + boff[1]);
    GLDS(bgp[2] + kt2, pt2 + 16384 + boff[2]);
    GLDS(bgp[3] + kt2, pt2 + 16384 + boff[3]);
    __builtin_amdgcn_sched_barrier(0);

    // ---- wait group 0 only (8 ph1 reads still in flight) ----
    asm volatile("s_waitcnt lgkmcnt(8)" ::: "memory");
    __builtin_amdgcn_sched_barrier(0);
    __builtin_amdgcn_s_setprio(1);
#pragma unroll
    for (int m = 0; m < 4; m++)
#pragma unroll
      for (int n = 0; n < 4; n++)
        acc[m][n] = __builtin_amdgcn_mfma_f32_16x16x32_bf16(a0[m], b0[n], acc[m][n], 0, 0, 0);
    __builtin_amdgcn_s_setprio(0);
    __builtin_amdgcn_sched_barrier(0);

    // ---- wait group 1 ----
    asm volatile("s_waitcnt lgkmcnt(0)" ::: "memory");
    __builtin_amdgcn_sched_barrier(0);
    __builtin_amdgcn_s_setprio(1);
#pragma unroll
    for (int m = 0; m < 4; m++)
#pragma unroll
      for (int n = 0; n < 4; n++)
        acc[m][n] = __builtin_amdgcn_mfma_f32_16x16x32_bf16(a1[m], b1[n], acc[m][n], 0, 0, 0);
    __builtin_amdgcn_s_setprio(0);

    // ---- tile boundary: own t+1 loads landed (6 of t+2 stay in flight) ----
    asm volatile("s_waitcnt vmcnt(6)" ::: "memory");
    __builtin_amdgcn_sched_barrier(0);
    __builtin_amdgcn_s_barrier();  // publishes t+1 to all; frees buffer t

    char* tmp = pt0; pt0 = pt1; pt1 = pt2; pt2 = tmp;
  }

  asm volatile("s_waitcnt vmcnt(0)" ::: "memory");  // drain dead tail stages

  // epilogue: kv = bf16(exp(-gamma * max(f2 + p2 - 2*dot, 0)))
  float p2v[4];
#pragma unroll
  for (int n = 0; n < 4; n++) p2v[n] = p2[bn * 256 + wc * 64 + n * 16 + l16];
#pragma unroll
  for (int m = 0; m < 4; m++) {
#pragma unroll
    for (int j = 0; j < 4; j++) {
      int grow = bm * 128 + wr * 64 + m * 16 + q * 4 + j;
      float f2v = f2[grow];
      __hip_bfloat16* kvp = kv + (size_t)grow * 4096 + bn * 256 + wc * 64 + l16;
#pragma unroll
      for (int n = 0; n < 4; n++) {
        float d2 = fmaxf(f2v + p2v[n] - 2.0f * acc[m][n][j], 0.f);
        kvp[n * 16] = __float2bfloat16(__expf(-GAMMA * d2));
      }
    }
  }
}

// ---------------- Kernel 3: logits = kv @ head_w^T + b; log_softmax ----------------
__global__ __launch_bounds__(256) void head_ls_k(
    const __hip_bfloat16* __restrict__ kv, const float* __restrict__ hw,
    const float* __restrict__ hb, float* __restrict__ out) {
  const int b = blockIdx.x, tid = threadIdx.x;
  const ushort4* kvr = (const ushort4*)(kv + (size_t)b * 4096);
  float part[10];
#pragma unroll
  for (int c = 0; c < 10; c++) part[c] = 0.f;
#pragma unroll
  for (int k = 0; k < 4; k++) {
    int idx = tid + k * 256;
    ushort4 v = kvr[idx];
    float a0 = bf2f(v.x), a1 = bf2f(v.y), a2 = bf2f(v.z), a3 = bf2f(v.w);
#pragma unroll
    for (int c = 0; c < 10; c++) {
      float4 w = *(const float4*)(hw + c * 4096 + idx * 4);
      part[c] += a0 * w.x + a1 * w.y + a2 * w.z + a3 * w.w;
    }
  }
#pragma unroll
  for (int c = 0; c < 10; c++)
    for (int off = 32; off > 0; off >>= 1) part[c] += __shfl_down(part[c], off);
  __shared__ float red[4][10];
  if ((tid & 63) == 0) {
#pragma unroll
    for (int c = 0; c < 10; c++) red[tid >> 6][c] = part[c];
  }
  __syncthreads();
  if (tid == 0) {
    float l[10], m = -1e30f;
#pragma unroll
    for (int c = 0; c < 10; c++) {
      l[c] = red[0][c] + red[1][c] + red[2][c] + red[3][c] + hb[c];
      m = fmaxf(m, l[c]);
    }
    float s = 0.f;
#pragma unroll
    for (int c = 0; c < 10; c++) s += __expf(l[c] - m);
    float lse = logf(s);
#pragma unroll
    for (int c = 0; c < 10; c++) out[(size_t)b * 10 + c] = l[c] - m - lse;
  }
}

extern "C" void kernel_launch(void* const* d_in, const int* in_sizes, int n_in,
                              void* d_out, int out_size, void* d_ws, size_t ws_size,
                              hipStream_t stream) {
  const float* x      = (const float*)d_in[0];
  const float* protos = (const float*)d_in[1];
  const float* conv_w = (const float*)d_in[2];
  const float* conv_b = (const float*)d_in[3];
  const float* head_w = (const float*)d_in[4];
  const float* head_b = (const float*)d_in[5];
  float* out = (float*)d_out;
  char* ws = (char*)d_ws;

  __hip_bfloat16* pB  = (__hip_bfloat16*)ws;                     // 4096x4096 bf16 = 32 MB
  __hip_bfloat16* fA  = (__hip_bfloat16*)(ws + (32u << 20));     // 2048x4096 bf16 = 16 MB
  __hip_bfloat16* kvb = (__hip_bfloat16*)(ws + (48u << 20));     // 2048x4096 bf16 = 16 MB
  float* f2 = (float*)(ws + (64u << 20));                        // 2048 f32
  float* p2 = (float*)(ws + (64u << 20) + 8192);                 // 4096 f32

  hipLaunchKernelGGL(prep_k, dim3(6144), dim3(256), 0, stream,
                     x, conv_w, conv_b, fA, f2, protos, pB, p2);
  hipLaunchKernelGGL(gemm_kv_k, dim3(256), dim3(512), 0, stream, fA, pB, f2, p2, kvb);
  hipLaunchKernelGGL(head_ls_k, dim3(2048), dim3(256), 0, stream, kvb, head_w, head_b, out);
}

// Round 5
// 79.579 us; speedup vs baseline: 1.5158x; 1.3171x over previous
//
#include <hip/hip_runtime.h>
#include <hip/hip_bf16.h>
#include <stdint.h>

#define GAMMA 1e-4f

typedef int i32x4 __attribute__((ext_vector_type(4)));
typedef int i32x8 __attribute__((ext_vector_type(8)));
typedef float f32x4 __attribute__((ext_vector_type(4)));

__device__ __forceinline__ float bf2f(unsigned short u) {
  unsigned int x = ((unsigned int)u) << 16;
  float f; __builtin_memcpy(&f, &x, 4);
  return f;
}

// bit-exact float -> OCP e4m3fn (RNE, satfinite). No hip_fp8.h dependency.
__device__ __forceinline__ unsigned char f2e4m3(float x) {
  float a = fabsf(x);
  unsigned char s = x < 0.f ? 0x80 : 0;
  a = fminf(a, 448.f);
  if (a < 0.015625f) {                    // subnormal region, ulp 2^-9
    int q = (int)rintf(a * 512.f);        // 0..8 (8 == 2^-6 == first normal)
    return s | (unsigned char)q;
  }
  unsigned int u; __builtin_memcpy(&u, &a, 4);
  u += 0x7FFFFu + ((u >> 20) & 1);        // RNE to 3 mantissa bits
  u &= 0xFFF00000u;
  int e2 = (int)(u >> 23) - 127;          // -6..8
  unsigned int mant = (u >> 20) & 7;
  return s | (unsigned char)(((e2 + 7) << 3) | mant);
}

__device__ __forceinline__ unsigned int pack4(float a, float b, float c, float d) {
  return (unsigned)f2e4m3(a) | ((unsigned)f2e4m3(b) << 8) |
         ((unsigned)f2e4m3(c) << 16) | ((unsigned)f2e4m3(d) << 24);
}

// ---------------- Kernel 1: merged prep (fp8 outputs, fp32 norms) ----------------
__global__ __launch_bounds__(256) void prep_k(
    const float* __restrict__ x, const float* __restrict__ cw,
    const float* __restrict__ cb, unsigned char* __restrict__ fA8,
    float* __restrict__ f2, const float* __restrict__ pr,
    unsigned char* __restrict__ pB8, float* __restrict__ p2) {
  const int tid = threadIdx.x;
  __shared__ float red[4];
  if (blockIdx.x < 4096) {
    const int j = blockIdx.x;
    const float4* src = (const float4*)(pr + (size_t)j * 4096);
    float ssq = 0.f;
    unsigned int w4[4];
#pragma unroll
    for (int k = 0; k < 4; k++) {
      float4 v = src[tid * 4 + k];
      ssq += v.x * v.x + v.y * v.y + v.z * v.z + v.w * v.w;
      w4[k] = pack4(v.x, v.y, v.z, v.w);
    }
    *(uint4*)(pB8 + (size_t)j * 4096 + tid * 16) = make_uint4(w4[0], w4[1], w4[2], w4[3]);
    for (int off = 32; off > 0; off >>= 1) ssq += __shfl_down(ssq, off);
    if ((tid & 63) == 0) red[tid >> 6] = ssq;
    __syncthreads();
    if (tid == 0) p2[j] = red[0] + red[1] + red[2] + red[3];
  } else {
    const int b = blockIdx.x - 4096;
    __shared__ float swb[20];
    if (tid < 16) swb[tid] = cw[tid];
    else if (tid < 20) swb[tid] = cb[tid - 16];
    __syncthreads();
    float w[16], bias[4];
#pragma unroll
    for (int i = 0; i < 16; i++) w[i] = swb[i];
#pragma unroll
    for (int c = 0; c < 4; c++) bias[c] = swb[16 + c];
    const float* xb = x + (size_t)b * 4096;
    unsigned char* fb8 = fA8 + (size_t)b * 4096;
    const int p0 = tid * 4;                 // 4 consecutive output positions
    const int h = p0 >> 5, w0 = p0 & 31;
    const float* r0 = xb + (2 * h) * 64 + 2 * w0;
    const float* r1 = r0 + 64;
    float4 a0 = *(const float4*)r0, a1 = *(const float4*)(r0 + 4);
    float4 c0 = *(const float4*)r1, c1 = *(const float4*)(r1 + 4);
    float ssq = 0.f;
#pragma unroll
    for (int c = 0; c < 4; c++) {
      float w00 = w[c * 4], w01 = w[c * 4 + 1], w10 = w[c * 4 + 2], w11 = w[c * 4 + 3];
      float v0 = bias[c] + a0.x * w00 + a0.y * w01 + c0.x * w10 + c0.y * w11;
      float v1 = bias[c] + a0.z * w00 + a0.w * w01 + c0.z * w10 + c0.w * w11;
      float v2 = bias[c] + a1.x * w00 + a1.y * w01 + c1.x * w10 + c1.y * w11;
      float v3 = bias[c] + a1.z * w00 + a1.w * w01 + c1.z * w10 + c1.w * w11;
      ssq += v0 * v0 + v1 * v1 + v2 * v2 + v3 * v3;
      *(unsigned int*)(fb8 + c * 1024 + p0) = pack4(v0, v1, v2, v3);
    }
    for (int off = 32; off > 0; off >>= 1) ssq += __shfl_down(ssq, off);
    if ((tid & 63) == 0) red[tid >> 6] = ssq;
    __syncthreads();
    if (tid == 0) f2[b] = red[0] + red[1] + red[2] + red[3];
  }
}

// ---------------- Kernel 2: fp8 GEMM (mfma_scale, unit scales) + RBF epilogue ---------
// BM=128, BN=256, BK=128 (fp8 -> 48KB/tile, same LDS as before, half the tiles).
// LDS layout: A = [kq][128 rows][32B] (kq stride 4096), B = [kq][256 rows][32B]
// (stride 8192), phys = logical ^ ((kq&1)<<4)  (both-sides swizzle, rule #21).
#define SWZA(o) ((o) ^ ((((o) >> 12) & 1) << 4))
#define SWZB(o) ((o) ^ ((((o) >> 13) & 1) << 4))
#define TILE_BYTES 49152

#define GLDS(gsrc, ldst)                                                    \
  __builtin_amdgcn_global_load_lds(                                         \
      (__attribute__((address_space(1))) void*)(void*)(gsrc),               \
      (__attribute__((address_space(3))) void*)(ldst), 16, 0, 0)

#define MFMA8(a, b, c)                                                      \
  __builtin_amdgcn_mfma_scale_f32_16x16x128_f8f6f4(                         \
      (a), (b), (c), 0, 0, 0, 0x7f7f7f7fu, 0, 0x7f7f7f7fu)

__device__ __forceinline__ i32x8 read32(const char* p0, const char* p1) {
  i32x4 lo = *(const i32x4*)p0;
  i32x4 hi = *(const i32x4*)p1;
  return __builtin_shufflevector(lo, hi, 0, 1, 2, 3, 4, 5, 6, 7);
}

#define TILE_BODY(PT, DO_STAGE, KB, VMWAIT_CODE)                            \
  {                                                                         \
    i32x8 av0, av1, av2, av3, bv0, bv1, bv2, bv3;                           \
    __builtin_amdgcn_sched_barrier(0);                                      \
    av0 = read32((PT) + arlo[0], (PT) + arhi[0]);                           \
    av1 = read32((PT) + arlo[1], (PT) + arhi[1]);                           \
    av2 = read32((PT) + arlo[2], (PT) + arhi[2]);                           \
    av3 = read32((PT) + arlo[3], (PT) + arhi[3]);                           \
    bv0 = read32((PT) + brlo[0], (PT) + brhi[0]);                           \
    bv1 = read32((PT) + brlo[1], (PT) + brhi[1]);                           \
    __builtin_amdgcn_sched_barrier(0);                                      \
    if (DO_STAGE) {                                                         \
      GLDS(agp[0] + (KB), pt2 + aoff[0]);                                   \
      GLDS(agp[1] + (KB), pt2 + aoff[1]);                                   \
      GLDS(bgp[0] + (KB), pt2 + 16384 + boff[0]);                           \
    }                                                                       \
    bv2 = read32((PT) + brlo[2], (PT) + brhi[2]);                           \
    bv3 = read32((PT) + brlo[3], (PT) + brhi[3]);                           \
    if (DO_STAGE) {                                                         \
      GLDS(bgp[1] + (KB), pt2 + 16384 + boff[1]);                           \
      GLDS(bgp[2] + (KB), pt2 + 16384 + boff[2]);                           \
      GLDS(bgp[3] + (KB), pt2 + 16384 + boff[3]);                           \
    }                                                                       \
    __builtin_amdgcn_sched_barrier(0);                                      \
    asm volatile("s_waitcnt lgkmcnt(4)" ::: "memory");                      \
    __builtin_amdgcn_sched_barrier(0);                                      \
    __builtin_amdgcn_s_setprio(1);                                          \
    acc[0][0] = MFMA8(av0, bv0, acc[0][0]);                                 \
    acc[0][1] = MFMA8(av0, bv1, acc[0][1]);                                 \
    acc[1][0] = MFMA8(av1, bv0, acc[1][0]);                                 \
    acc[1][1] = MFMA8(av1, bv1, acc[1][1]);                                 \
    acc[2][0] = MFMA8(av2, bv0, acc[2][0]);                                 \
    acc[2][1] = MFMA8(av2, bv1, acc[2][1]);                                 \
    acc[3][0] = MFMA8(av3, bv0, acc[3][0]);                                 \
    acc[3][1] = MFMA8(av3, bv1, acc[3][1]);                                 \
    __builtin_amdgcn_s_setprio(0);                                          \
    __builtin_amdgcn_sched_barrier(0);                                      \
    asm volatile("s_waitcnt lgkmcnt(0)" ::: "memory");                      \
    __builtin_amdgcn_sched_barrier(0);                                      \
    __builtin_amdgcn_s_setprio(1);                                          \
    acc[0][2] = MFMA8(av0, bv2, acc[0][2]);                                 \
    acc[0][3] = MFMA8(av0, bv3, acc[0][3]);                                 \
    acc[1][2] = MFMA8(av1, bv2, acc[1][2]);                                 \
    acc[1][3] = MFMA8(av1, bv3, acc[1][3]);                                 \
    acc[2][2] = MFMA8(av2, bv2, acc[2][2]);                                 \
    acc[2][3] = MFMA8(av2, bv3, acc[2][3]);                                 \
    acc[3][2] = MFMA8(av3, bv2, acc[3][2]);                                 \
    acc[3][3] = MFMA8(av3, bv3, acc[3][3]);                                 \
    __builtin_amdgcn_s_setprio(0);                                          \
    VMWAIT_CODE;                                                            \
    __builtin_amdgcn_sched_barrier(0);                                      \
  }

__global__ __launch_bounds__(512, 1) void gemm_kv_k(
    const unsigned char* __restrict__ A, const unsigned char* __restrict__ B,
    const float* __restrict__ f2, const float* __restrict__ p2,
    __hip_bfloat16* __restrict__ kv) {
  __shared__ __align__(16) char lds[3 * TILE_BYTES];  // 144 KiB
  const int tid = threadIdx.x;
  const int wave = tid >> 6, lane = tid & 63;
  const int q = lane >> 4, l16 = lane & 15;
  const int wr = wave >> 2, wc = wave & 3;

  // XCD-aware tile swizzle: 256 WGs = 8 XCDs x 32
  const int wg = blockIdx.x;
  const int xcd = wg & 7, loc = wg >> 3;
  const int bm = (xcd & 1) * 8 + (loc & 7);
  const int bn = (xcd >> 1) * 4 + (loc >> 3);

  // staging: linear LDS dest, inverse-swizzled global src (rule #21)
  const unsigned char* agp[2];
  const unsigned char* bgp[4];
  int aoff[2], boff[4];
#pragma unroll
  for (int i = 0; i < 2; i++) {
    int phys = (tid + i * 512) * 16;
    aoff[i] = phys;
    int lg = SWZA(phys);
    int kq = lg >> 12, rw = (lg & 4095) >> 5, kl = lg & 31;
    agp[i] = A + (size_t)(bm * 128 + rw) * 4096 + kq * 32 + kl;
  }
#pragma unroll
  for (int i = 0; i < 4; i++) {
    int phys = (tid + i * 512) * 16;
    boff[i] = phys;
    int lg = SWZB(phys);
    int kq = lg >> 13, rw = (lg & 8191) >> 5, kl = lg & 31;
    bgp[i] = B + (size_t)(bn * 256 + rw) * 4096 + kq * 32 + kl;
  }

  // fragment read addresses: lane holds row=l16(+16m), k-quarter q, 32 consecutive K
  int arlo[4], arhi[4], brlo[4], brhi[4];
#pragma unroll
  for (int m = 0; m < 4; m++) {
    int lg = q * 4096 + (wr * 64 + m * 16 + l16) * 32;
    arlo[m] = SWZA(lg);
    arhi[m] = SWZA(lg + 16);
  }
#pragma unroll
  for (int n = 0; n < 4; n++) {
    int lg = q * 8192 + (wc * 64 + n * 16 + l16) * 32;
    brlo[n] = 16384 + SWZB(lg);
    brhi[n] = 16384 + SWZB(lg + 16);
  }

  f32x4 acc[4][4] = {};

  char* pt0 = lds;
  char* pt1 = lds + TILE_BYTES;
  char* pt2 = lds + 2 * TILE_BYTES;

  // prologue: stage tiles 0 and 1 (K-tile stride = 128 bytes)
#pragma unroll
  for (int i = 0; i < 2; i++) GLDS(agp[i], pt0 + aoff[i]);
#pragma unroll
  for (int i = 0; i < 4; i++) GLDS(bgp[i], pt0 + 16384 + boff[i]);
#pragma unroll
  for (int i = 0; i < 2; i++) GLDS(agp[i] + 128, pt1 + aoff[i]);
#pragma unroll
  for (int i = 0; i < 4; i++) GLDS(bgp[i] + 128, pt1 + 16384 + boff[i]);
  asm volatile("s_waitcnt vmcnt(6)" ::: "memory");
  __builtin_amdgcn_s_barrier();

#pragma unroll 1
  for (int t = 0; t < 30; ++t) {
    const size_t kb2 = (size_t)(t + 2) * 128;
    TILE_BODY(pt0, 1, kb2,
              asm volatile("s_waitcnt vmcnt(6)" ::: "memory");
              __builtin_amdgcn_sched_barrier(0);
              __builtin_amdgcn_s_barrier());
    char* tmp = pt0; pt0 = pt1; pt1 = pt2; pt2 = tmp;
  }
  // tile 30 (tile 31 still in flight -> drain fully, publish)
  TILE_BODY(pt0, 0, 0,
            asm volatile("s_waitcnt vmcnt(0)" ::: "memory");
            __builtin_amdgcn_sched_barrier(0);
            __builtin_amdgcn_s_barrier());
  pt0 = pt1;
  // tile 31
  TILE_BODY(pt0, 0, 0, );

  // epilogue: kv = bf16(exp(-gamma * max(f2 + p2 - 2*dot, 0)))
  // C/D layout (16x16): col = lane&15, row = (lane>>4)*4 + j
  float p2v[4];
#pragma unroll
  for (int n = 0; n < 4; n++) p2v[n] = p2[bn * 256 + wc * 64 + n * 16 + l16];
#pragma unroll
  for (int m = 0; m < 4; m++) {
#pragma unroll
    for (int j = 0; j < 4; j++) {
      int grow = bm * 128 + wr * 64 + m * 16 + q * 4 + j;
      float f2v = f2[grow];
      __hip_bfloat16* kvp = kv + (size_t)grow * 4096 + bn * 256 + wc * 64 + l16;
#pragma unroll
      for (int n = 0; n < 4; n++) {
        float d2 = fmaxf(f2v + p2v[n] - 2.0f * acc[m][n][j], 0.f);
        kvp[n * 16] = __float2bfloat16(__expf(-GAMMA * d2));
      }
    }
  }
}

// ---------------- Kernel 3: logits = kv @ head_w^T + b; log_softmax (4 rows/block) ----
__global__ __launch_bounds__(256) void head_ls_k(
    const __hip_bfloat16* __restrict__ kv, const float* __restrict__ hw,
    const float* __restrict__ hb, float* __restrict__ out) {
  const int bb = blockIdx.x * 4;
  const int tid = threadIdx.x;
  float part[4][10];
#pragma unroll
  for (int r = 0; r < 4; r++)
#pragma unroll
    for (int c = 0; c < 10; c++) part[r][c] = 0.f;
#pragma unroll
  for (int k = 0; k < 4; k++) {
    int idx = tid + k * 256;  // ushort4 chunk index, 0..1023
    float4 w[10];
#pragma unroll
    for (int c = 0; c < 10; c++) w[c] = *(const float4*)(hw + c * 4096 + idx * 4);
#pragma unroll
    for (int r = 0; r < 4; r++) {
      ushort4 v = ((const ushort4*)(kv + (size_t)(bb + r) * 4096))[idx];
      float a0 = bf2f(v.x), a1 = bf2f(v.y), a2 = bf2f(v.z), a3 = bf2f(v.w);
#pragma unroll
      for (int c = 0; c < 10; c++)
        part[r][c] += a0 * w[c].x + a1 * w[c].y + a2 * w[c].z + a3 * w[c].w;
    }
  }
#pragma unroll
  for (int r = 0; r < 4; r++)
#pragma unroll
    for (int c = 0; c < 10; c++)
      for (int off = 32; off > 0; off >>= 1) part[r][c] += __shfl_down(part[r][c], off);
  __shared__ float red[4][4][10];
  if ((tid & 63) == 0) {
#pragma unroll
    for (int r = 0; r < 4; r++)
#pragma unroll
      for (int c = 0; c < 10; c++) red[tid >> 6][r][c] = part[r][c];
  }
  __syncthreads();
  if (tid < 4) {
    const int r = tid;
    float l[10], m = -1e30f;
#pragma unroll
    for (int c = 0; c < 10; c++) {
      l[c] = red[0][r][c] + red[1][r][c] + red[2][r][c] + red[3][r][c] + hb[c];
      m = fmaxf(m, l[c]);
    }
    float s = 0.f;
#pragma unroll
    for (int c = 0; c < 10; c++) s += __expf(l[c] - m);
    float lse = logf(s);
#pragma unroll
    for (int c = 0; c < 10; c++) out[(size_t)(bb + r) * 10 + c] = l[c] - m - lse;
  }
}

extern "C" void kernel_launch(void* const* d_in, const int* in_sizes, int n_in,
                              void* d_out, int out_size, void* d_ws, size_t ws_size,
                              hipStream_t stream) {
  const float* x      = (const float*)d_in[0];
  const float* protos = (const float*)d_in[1];
  const float* conv_w = (const float*)d_in[2];
  const float* conv_b = (const float*)d_in[3];
  const float* head_w = (const float*)d_in[4];
  const float* head_b = (const float*)d_in[5];
  float* out = (float*)d_out;
  char* ws = (char*)d_ws;

  unsigned char* pB8  = (unsigned char*)ws;                      // 4096x4096 fp8 = 16 MB
  unsigned char* fA8  = (unsigned char*)(ws + (16u << 20));      // 2048x4096 fp8 =  8 MB
  __hip_bfloat16* kvb = (__hip_bfloat16*)(ws + (24u << 20));     // 2048x4096 bf16 = 16 MB
  float* f2 = (float*)(ws + (40u << 20));                        // 2048 f32
  float* p2 = (float*)(ws + (40u << 20) + 8192);                 // 4096 f32

  hipLaunchKernelGGL(prep_k, dim3(6144), dim3(256), 0, stream,
                     x, conv_w, conv_b, fA8, f2, protos, pB8, p2);
  hipLaunchKernelGGL(gemm_kv_k, dim3(256), dim3(512), 0, stream, fA8, pB8, f2, p2, kvb);
  hipLaunchKernelGGL(head_ls_k, dim3(512), dim3(256), 0, stream, kvb, head_w, head_b, out);
}